// Round 17
// baseline (511.184 us; speedup 1.0000x reference)
//
#include <hip/hip_runtime.h>
#include <cstdint>
#include <cstddef>

#define S_LEN 250
#define BATCH 256
#define CIN   700
#define HID   256
#define OUT_N 20
#define KSTEPS 22   // ceil(700/32)

typedef __attribute__((ext_vector_type(8))) short bf16x8;
typedef __attribute__((ext_vector_type(4))) float f32x4;

__device__ __forceinline__ ushort f2bf_rne(float f) {
    uint u = __float_as_uint(f);
    uint r = (u + 0x7FFFu + ((u >> 16) & 1u)) >> 16;
    return (ushort)r;
}
__device__ __forceinline__ float bf2f(ushort h) {
    return __uint_as_float(((uint)h) << 16);
}

// ---------------------------------------------------------------------------
// Kernel 1: input projection GEMM via bf16x3 split MFMA (R14 form — best
// measured: ~158us; bit-identical P).
// ---------------------------------------------------------------------------
__global__ __launch_bounds__(256) void proj_mfma(
    const float* __restrict__ x,
    const float* __restrict__ Wf, const float* __restrict__ Wb,
    const float* __restrict__ biasf, const float* __restrict__ biasb,
    float* __restrict__ P)
{
    __shared__ ushort AsH[128][40];
    __shared__ ushort AsL[128][40];
    __shared__ ushort BsH[256][40];
    __shared__ ushort BsL[256][40];

    const int nt = blockIdx.x;          // 0 = fw cols, 1 = bw cols
    const int mt = blockIdx.y;          // 0..499
    const int m0 = mt * 128;
    const float* W   = nt ? Wb : Wf;
    const float* bia = nt ? biasb : biasf;

    const int tid  = threadIdx.x;
    const int lane = tid & 63;
    const int wv   = tid >> 6;          // wave 0..3
    const int wr   = wv >> 1;           // row-half
    const int wc   = wv & 1;            // col-half (128 cols each)
    const int l15  = lane & 15;
    const int l4   = lane >> 4;

    const int as  = tid & 7;            // A k-slot (4 floats)
    const int arr = tid >> 3;           // A row 0..31 (x4 row-groups)

    f32x4 acc[4][8];
#pragma unroll
    for (int i = 0; i < 4; i++)
#pragma unroll
        for (int j = 0; j < 8; j++)
            acc[i][j] = (f32x4){0.f, 0.f, 0.f, 0.f};

    float4 av[4];
    float bv[32];

#define PROJ_LOAD(K0_) do {                                                   \
        const int ka_ = (K0_) + as * 4;                                       \
        const bool aok_ = (ka_ + 3) < CIN;                                    \
        _Pragma("unroll")                                                     \
        for (int i_ = 0; i_ < 4; i_++) {                                      \
            av[i_] = make_float4(0.f, 0.f, 0.f, 0.f);                         \
            if (aok_)                                                         \
                av[i_] = *(const float4*)&x[(size_t)(m0 + arr + 32 * i_) * CIN + ka_]; \
        }                                                                     \
        _Pragma("unroll")                                                     \
        for (int j_ = 0; j_ < 32; j_++) {                                     \
            const int kb_ = (K0_) + j_;                                       \
            bv[j_] = (kb_ < CIN) ? W[(size_t)kb_ * HID + tid] : 0.f;          \
        }                                                                     \
    } while (0)

#define PROJ_CVT_WRITE() do {                                                 \
        _Pragma("unroll")                                                     \
        for (int i_ = 0; i_ < 4; i_++) {                                      \
            const int row_ = arr + 32 * i_;                                   \
            ushort4 h_, l_;                                                   \
            h_.x = f2bf_rne(av[i_].x); l_.x = f2bf_rne(__fsub_rn(av[i_].x, bf2f(h_.x))); \
            h_.y = f2bf_rne(av[i_].y); l_.y = f2bf_rne(__fsub_rn(av[i_].y, bf2f(h_.y))); \
            h_.z = f2bf_rne(av[i_].z); l_.z = f2bf_rne(__fsub_rn(av[i_].z, bf2f(h_.z))); \
            h_.w = f2bf_rne(av[i_].w); l_.w = f2bf_rne(__fsub_rn(av[i_].w, bf2f(h_.w))); \
            *(ushort4*)&AsH[row_][as * 4] = h_;                               \
            *(ushort4*)&AsL[row_][as * 4] = l_;                               \
        }                                                                     \
        _Pragma("unroll")                                                     \
        for (int q_ = 0; q_ < 8; q_++) {                                      \
            ushort4 h_, l_;                                                   \
            float v0_ = bv[q_ * 4 + 0], v1_ = bv[q_ * 4 + 1];                 \
            float v2_ = bv[q_ * 4 + 2], v3_ = bv[q_ * 4 + 3];                 \
            h_.x = f2bf_rne(v0_); l_.x = f2bf_rne(__fsub_rn(v0_, bf2f(h_.x))); \
            h_.y = f2bf_rne(v1_); l_.y = f2bf_rne(__fsub_rn(v1_, bf2f(h_.y))); \
            h_.z = f2bf_rne(v2_); l_.z = f2bf_rne(__fsub_rn(v2_, bf2f(h_.z))); \
            h_.w = f2bf_rne(v3_); l_.w = f2bf_rne(__fsub_rn(v3_, bf2f(h_.w))); \
            *(ushort4*)&BsH[tid][q_ * 4] = h_;                               \
            *(ushort4*)&BsL[tid][q_ * 4] = l_;                               \
        }                                                                     \
    } while (0)

    PROJ_LOAD(0);
    PROJ_CVT_WRITE();

    for (int kt = 0; kt < KSTEPS; kt++) {
        __syncthreads();                 // tile kt writes visible
        if (kt + 1 < KSTEPS)
            PROJ_LOAD((kt + 1) * 32);    // next loads land during MFMA

#pragma unroll
        for (int fc = 0; fc < 8; fc++) {
            const bf16x8 bHf = *(const bf16x8*)&BsH[wc * 128 + fc * 16 + l15][l4 * 8];
            const bf16x8 bLf = *(const bf16x8*)&BsL[wc * 128 + fc * 16 + l15][l4 * 8];
#pragma unroll
            for (int fr = 0; fr < 4; fr++) {
                const bf16x8 aHf = *(const bf16x8*)&AsH[wr * 64 + fr * 16 + l15][l4 * 8];
                const bf16x8 aLf = *(const bf16x8*)&AsL[wr * 64 + fr * 16 + l15][l4 * 8];
                acc[fr][fc] = __builtin_amdgcn_mfma_f32_16x16x32_bf16(
                    aHf, bHf, acc[fr][fc], 0, 0, 0);
                acc[fr][fc] = __builtin_amdgcn_mfma_f32_16x16x32_bf16(
                    aHf, bLf, acc[fr][fc], 0, 0, 0);
                acc[fr][fc] = __builtin_amdgcn_mfma_f32_16x16x32_bf16(
                    aLf, bHf, acc[fr][fc], 0, 0, 0);
            }
        }

        __syncthreads();                 // all reads of tile kt done
        if (kt + 1 < KSTEPS)
            PROJ_CVT_WRITE();
    }

#undef PROJ_LOAD
#undef PROJ_CVT_WRITE

#pragma unroll
    for (int fc = 0; fc < 8; fc++) {
        const int col = wc * 128 + fc * 16 + l15;      // 0..255 in direction
        const float bvs = bia[col];
#pragma unroll
        for (int fr = 0; fr < 4; fr++) {
#pragma unroll
            for (int j = 0; j < 4; j++) {
                const int row = m0 + wr * 64 + fr * 16 + l4 * 4 + j;
                P[(size_t)row * 512 + nt * HID + col] =
                    __fadd_rn(acc[fr][fc][j], bvs);
            }
        }
    }
}

// ---------------------------------------------------------------------------
// Kernel 2: MFMA scan, 16-WAVE occupancy redesign. Block = (16 batches, 1
// dir), 1024 threads = 16 waves; wave w owns cols [w*16, w*16+16).
// W_rec hi/lo: kt 0-3 in registers (32 VGPR), kt 4-7 in LDS (128KB; total
// LDS 152KB). Per-wave regs ~114 <= 128 -> 4 waves/SIMD (2x prior occupancy)
// to overlap the serial LIF/barrier phases with the MFMA pipe.
// Numerics: per-column acc chain order (kt0 h,l ... kt7 h,l) and all f2bf
// values identical to R6/R14 -> bit-identical spikes. Readout DELAYED (reads
// Sp[prev]; bit-exact sequence, measured neutral+correct in R13), computed
// on even waves over 32-col pairs (avoids cross-wave same-step visibility).
// ---------------------------------------------------------------------------
__global__ __launch_bounds__(1024, 4) void scan_mfma16(
    const float* __restrict__ P,
    const float* __restrict__ Wrecf, const float* __restrict__ brecf,
    const float* __restrict__ taumf, const float* __restrict__ tauaf,
    const float* __restrict__ Wrecb, const float* __restrict__ brecb,
    const float* __restrict__ taumb, const float* __restrict__ tauab,
    const float* __restrict__ Wout, const float* __restrict__ taumo,
    float* __restrict__ Pst)
{
    const int g  = blockIdx.x;          // batch group: b0..b0+15
    const int d  = blockIdx.y;          // 0 = fw, 1 = bw
    const int b0 = g * 16;
    const bool fw = (d == 0);

    const int tid  = threadIdx.x;       // 0..1023
    const int lane = tid & 63;
    const int w    = tid >> 6;          // wave 0..15
    const int l15  = lane & 15;
    const int l4   = lane >> 4;
    const int c    = w * 16 + l15;      // this thread's column 0..255

    __shared__ ushort Sp[2][16][264];   // spike tiles (16.5 KB)
    __shared__ ushort WH[256][132];     // W_rec hi, k=128..255 (66 KB)
    __shared__ ushort WL[256][132];     // W_rec lo, k=128..255 (66 KB)

    {   // zero both spike buffers (step -1 spikes = 0)
        ushort* p = &Sp[0][0][0];
        for (int i = tid; i < 2 * 16 * 264; i += 1024) p[i] = 0;
    }

    const float* Wrec = fw ? Wrecf : Wrecb;

    // ---- fill W-LDS for k = 128..255 (coalesced over columns)
    {
        const int cc = tid & 255;
        const int kq = tid >> 8;        // 0..3
        for (int k2 = 0; k2 < 32; k2++) {
            const int k = 128 + kq * 32 + k2;
            const float v = Wrec[(size_t)k * HID + cc];
            const ushort h = f2bf_rne(v);
            const ushort l = f2bf_rne(__fsub_rn(v, bf2f(h)));
            WH[cc][k - 128] = h;
            WL[cc][k - 128] = l;
        }
    }

    // ---- W_rec fragments kt=0..3 (hi+lo), register resident (32 VGPR)
    bf16x8 whf[4], wlf[4];
#pragma unroll
    for (int kt = 0; kt < 4; kt++) {
#pragma unroll
        for (int j = 0; j < 8; j++) {
            const float v = Wrec[(size_t)(kt * 32 + l4 * 8 + j) * HID + c];
            const ushort h = f2bf_rne(v);
            const ushort l = f2bf_rne(__fsub_rn(v, bf2f(h)));
            whf[kt][j] = (short)h;
            wlf[kt][j] = (short)l;
        }
    }

    // ---- W_out fragments (even waves: 32-col k-slice [w*16, w*16+32))
    bf16x8 woh[2], wol[2];
#pragma unroll
    for (int t = 0; t < 2; t++)
#pragma unroll
        for (int j = 0; j < 8; j++) { woh[t][j] = 0; wol[t][j] = 0; }
    if (!(w & 1)) {
#pragma unroll
        for (int t = 0; t < 2; t++) {
            const int o = t * 16 + l15;
#pragma unroll
            for (int j = 0; j < 8; j++) {
                float v = 0.f;
                if (o < OUT_N)
                    v = Wout[(size_t)(d * HID + w * 16 + l4 * 8 + j) * OUT_N + o];
                const ushort h = f2bf_rne(v);
                const ushort l = f2bf_rne(__fsub_rn(v, bf2f(h)));
                woh[t][j] = (short)h;
                wol[t][j] = (short)l;
            }
        }
    }

    // ---- LIF constants for this thread's single column
    const float alpha = expf(__fdiv_rn(-1.f, fw ? taumf[c] : taumb[c]));
    const float ro    = expf(__fdiv_rn(-1.f, fw ? tauaf[c] : tauab[c]));
    const float omA   = __fsub_rn(1.f, alpha);
    const float omR   = __fsub_rn(1.f, ro);
    const float brc   = fw ? brecf[c] : brecb[c];

    // ---- readout constants (even waves)
    float ao_[2] = {0.f, 0.f}, omo_[2] = {0.f, 0.f};
    if (!(w & 1)) {
#pragma unroll
        for (int t = 0; t < 2; t++) {
            const int o = t * 16 + l15;
            if (o < OUT_N) {
                ao_[t]  = expf(__fdiv_rn(-1.f, taumo[o]));
                omo_[t] = __fsub_rn(1.f, ao_[t]);
            }
        }
    }

    float mem[4], bbv[4], spkv[4], z[2][4];
#pragma unroll
    for (int j = 0; j < 4; j++) {
        mem[j] = 0.f; bbv[j] = 0.01f; spkv[j] = 0.f;
        z[0][j] = 0.f; z[1][j] = 0.f;
    }

    // pv prefetch for s=0
    float pv[4];
    {
        const int srow = fw ? 0 : (S_LEN - 1);
#pragma unroll
        for (int j = 0; j < 4; j++)
            pv[j] = P[((size_t)(b0 + l4 * 4 + j) * S_LEN + srow) * 512
                      + d * HID + c];
    }

    __syncthreads();   // W-LDS + Sp zeros visible

    for (int s = 0; s < S_LEN; s++) {
        const int cur = s & 1, prev = cur ^ 1;

        // prefetch next step's projection BEFORE the barrier (R6 proven form)
        float pv_next[4];
        {
            const int sn   = (s + 1 < S_LEN) ? s + 1 : S_LEN - 1;
            const int srow = fw ? sn : (S_LEN - 1 - sn);
#pragma unroll
            for (int j = 0; j < 4; j++)
                pv_next[j] = P[((size_t)(b0 + l4 * 4 + j) * S_LEN + srow) * 512
                               + d * HID + c];
        }

        __syncthreads();   // Sp[prev] complete from all waves

        // ---- recurrent GEMM: D[batch][col] += spk(prev) @ W_rec
        // chain order per column: kt0 h,l ... kt7 h,l  (identical to R6)
        f32x4 acc = (f32x4){0.f, 0.f, 0.f, 0.f};
#pragma unroll
        for (int kt = 0; kt < 4; kt++) {
            const bf16x8 a = *(const bf16x8*)&Sp[prev][l15][kt * 32 + l4 * 8];
            acc = __builtin_amdgcn_mfma_f32_16x16x32_bf16(a, whf[kt], acc, 0, 0, 0);
            acc = __builtin_amdgcn_mfma_f32_16x16x32_bf16(a, wlf[kt], acc, 0, 0, 0);
        }
#pragma unroll
        for (int kt = 4; kt < 8; kt++) {
            const bf16x8 a  = *(const bf16x8*)&Sp[prev][l15][kt * 32 + l4 * 8];
            const bf16x8 bh = *(const bf16x8*)&WH[c][(kt - 4) * 32 + l4 * 8];
            const bf16x8 bl = *(const bf16x8*)&WL[c][(kt - 4) * 32 + l4 * 8];
            acc = __builtin_amdgcn_mfma_f32_16x16x32_bf16(a, bh, acc, 0, 0, 0);
            acc = __builtin_amdgcn_mfma_f32_16x16x32_bf16(a, bl, acc, 0, 0, 0);
        }

        // ---- DELAYED readout (even waves): y_{s-1} from Sp[prev]
        if (!(w & 1)) {
            const bf16x8 ar = *(const bf16x8*)&Sp[prev][l15][w * 16 + l4 * 8];
            f32x4 S0 = (f32x4){0.f, 0.f, 0.f, 0.f};
            f32x4 S1 = (f32x4){0.f, 0.f, 0.f, 0.f};
            S0 = __builtin_amdgcn_mfma_f32_16x16x32_bf16(ar, woh[0], S0, 0, 0, 0);
            S0 = __builtin_amdgcn_mfma_f32_16x16x32_bf16(ar, wol[0], S0, 0, 0, 0);
            S1 = __builtin_amdgcn_mfma_f32_16x16x32_bf16(ar, woh[1], S1, 0, 0, 0);
            S1 = __builtin_amdgcn_mfma_f32_16x16x32_bf16(ar, wol[1], S1, 0, 0, 0);
#pragma unroll
            for (int j = 0; j < 4; j++) {
                z[0][j] = __fmaf_rn(ao_[0], z[0][j], __fmul_rn(omo_[0], S0[j]));
                z[1][j] = __fmaf_rn(ao_[1], z[1][j], __fmul_rn(omo_[1], S1[j]));
            }
        }

        // ---- adaptive-LIF update (exact reference rounding order)
#pragma unroll
        for (int j = 0; j < 4; j++) {
            const float dd = __fadd_rn(__fadd_rn(pv[j], acc[j]), brc);
            bbv[j] = __fadd_rn(__fmul_rn(ro, bbv[j]),
                               __fmul_rn(omR, spkv[j]));
            const float thr = __fadd_rn(0.01f, __fmul_rn(1.8f, bbv[j]));
            mem[j] = __fsub_rn(
                __fadd_rn(__fmul_rn(mem[j], alpha), __fmul_rn(omA, dd)),
                __fmul_rn(thr, spkv[j]));
            const bool sp = __fsub_rn(mem[j], thr) > 0.f;
            spkv[j] = sp ? 1.f : 0.f;
            Sp[cur][l4 * 4 + j][c] = sp ? (ushort)0x3F80 : (ushort)0;
        }

#pragma unroll
        for (int j = 0; j < 4; j++) pv[j] = pv_next[j];
    }

    __syncthreads();   // last step's spike writes (all waves) visible

    // ---- epilogue: final readout with y_{S-1} (spk(249) in buffer 1)
    if (!(w & 1)) {
        const bf16x8 ar = *(const bf16x8*)&Sp[1][l15][w * 16 + l4 * 8];
        f32x4 S0 = (f32x4){0.f, 0.f, 0.f, 0.f};
        f32x4 S1 = (f32x4){0.f, 0.f, 0.f, 0.f};
        S0 = __builtin_amdgcn_mfma_f32_16x16x32_bf16(ar, woh[0], S0, 0, 0, 0);
        S0 = __builtin_amdgcn_mfma_f32_16x16x32_bf16(ar, wol[0], S0, 0, 0, 0);
        S1 = __builtin_amdgcn_mfma_f32_16x16x32_bf16(ar, woh[1], S1, 0, 0, 0);
        S1 = __builtin_amdgcn_mfma_f32_16x16x32_bf16(ar, wol[1], S1, 0, 0, 0);
#pragma unroll
        for (int j = 0; j < 4; j++) {
            z[0][j] = __fmaf_rn(ao_[0], z[0][j], __fmul_rn(omo_[0], S0[j]));
            z[1][j] = __fmaf_rn(ao_[1], z[1][j], __fmul_rn(omo_[1], S1[j]));
        }

        // ---- stash readout partials (slice = w/2, same layout as before)
        float* stash = Pst + ((size_t)b0 * S_LEN) * 512 + d * HID;
        const int ws = w >> 1;
#pragma unroll
        for (int j = 0; j < 4; j++) {
            const int r = l4 * 4 + j;
            const int idx0 = ws * 320 + r * 16 + l15;
            stash[(size_t)(idx0 >> 8) * 512 + (idx0 & 255)] = z[0][j];
            if (l15 < 4) {
                const int idx1 = ws * 320 + 256 + r * 4 + l15;
                stash[(size_t)(idx1 >> 8) * 512 + (idx1 & 255)] = z[1][j];
            }
        }
    }
}

// ---------------------------------------------------------------------------
// Kernel 3: merge stashed partials + bias closed form + log_softmax.
// (slice order d 0..1, slice 0..7 — unchanged layout)
// ---------------------------------------------------------------------------
__global__ __launch_bounds__(64) void merge_out(
    const float* __restrict__ Pst, const float* __restrict__ bout,
    const float* __restrict__ taumo, float* __restrict__ out)
{
    const int bb = blockIdx.x;
    const int o  = threadIdx.x;         // active 0..19
    const int g  = bb >> 4, r = bb & 15;

    float val = 0.f, v = -3.0e38f;
    if (o < OUT_N) {
        float tot = 0.f;
#pragma unroll
        for (int d2 = 0; d2 < 2; d2++) {
            const float* stash = Pst + ((size_t)(g * 16) * S_LEN) * 512 + d2 * HID;
#pragma unroll
            for (int w2 = 0; w2 < 8; w2++) {
                const int idx = (o < 16) ? (w2 * 320 + r * 16 + o)
                                         : (w2 * 320 + 256 + r * 4 + (o - 16));
                tot = __fadd_rn(tot, stash[(size_t)(idx >> 8) * 512 + (idx & 255)]);
            }
        }
        const float aS = expf(__fdiv_rn(-(float)S_LEN, taumo[o]));
        val = __fadd_rn(tot, __fmul_rn(bout[o], __fsub_rn(1.f, aS)));
        v = val;
    }
    float mx = v;
#pragma unroll
    for (int d2 = 1; d2 < 64; d2 <<= 1)
        mx = fmaxf(mx, __shfl_xor(mx, d2, 64));
    float e = (o < OUT_N) ? expf(__fsub_rn(val, mx)) : 0.f;
#pragma unroll
    for (int d2 = 1; d2 < 64; d2 <<= 1)
        e += __shfl_xor(e, d2, 64);
    if (o < OUT_N)
        out[(size_t)bb * OUT_N + o] =
            __fsub_rn(__fsub_rn(val, mx), logf(e));
}

// ---------------------------------------------------------------------------
extern "C" void kernel_launch(void* const* d_in, const int* in_sizes, int n_in,
                              void* d_out, int out_size, void* d_ws, size_t ws_size,
                              hipStream_t stream) {
    const float* x         = (const float*)d_in[0];
    const float* W_in_f    = (const float*)d_in[1];
    const float* b_in_f    = (const float*)d_in[2];
    const float* W_rec_f   = (const float*)d_in[3];
    const float* b_rec_f   = (const float*)d_in[4];
    const float* tau_m_f   = (const float*)d_in[5];
    const float* tau_adp_f = (const float*)d_in[6];
    const float* W_in_b    = (const float*)d_in[7];
    const float* b_in_b    = (const float*)d_in[8];
    const float* W_rec_b   = (const float*)d_in[9];
    const float* b_rec_b   = (const float*)d_in[10];
    const float* tau_m_b   = (const float*)d_in[11];
    const float* tau_adp_b = (const float*)d_in[12];
    const float* W_out     = (const float*)d_in[13];
    const float* b_out     = (const float*)d_in[14];
    const float* tau_m_o   = (const float*)d_in[15];
    float* out = (float*)d_out;
    float* P   = (float*)d_ws;

    proj_mfma<<<dim3(2, 500), dim3(256), 0, stream>>>(
        x, W_in_f, W_in_b, b_in_f, b_in_b, P);
    scan_mfma16<<<dim3(16, 2), dim3(1024), 0, stream>>>(
        P, W_rec_f, b_rec_f, tau_m_f, tau_adp_f,
        W_rec_b, b_rec_b, tau_m_b, tau_adp_b,
        W_out, tau_m_o, P);
    merge_out<<<dim3(BATCH), dim3(64), 0, stream>>>(
        P, b_out, tau_m_o, out);
}

// Round 18
// 509.969 us; speedup vs baseline: 1.0024x; 1.0024x over previous
//
#include <hip/hip_runtime.h>
#include <cstdint>
#include <cstddef>

#define S_LEN 250
#define BATCH 256
#define CIN   700
#define HID   256
#define OUT_N 20
#define KSTEPS 22   // ceil(700/32)

typedef __attribute__((ext_vector_type(8))) short bf16x8;
typedef __attribute__((ext_vector_type(4))) float f32x4;
typedef __attribute__((ext_vector_type(4))) int   i32x4;

__device__ __forceinline__ ushort f2bf_rne(float f) {
    uint u = __float_as_uint(f);
    uint r = (u + 0x7FFFu + ((u >> 16) & 1u)) >> 16;
    return (ushort)r;
}
__device__ __forceinline__ float bf2f(ushort h) {
    return __uint_as_float(((uint)h) << 16);
}

// ---------------------------------------------------------------------------
// Kernel 1: input projection GEMM via bf16x3 split MFMA (R14/R16 form — best
// measured ~158us; bit-identical P). FROZEN.
// ---------------------------------------------------------------------------
__global__ __launch_bounds__(256) void proj_mfma(
    const float* __restrict__ x,
    const float* __restrict__ Wf, const float* __restrict__ Wb,
    const float* __restrict__ biasf, const float* __restrict__ biasb,
    float* __restrict__ P)
{
    __shared__ ushort AsH[128][40];
    __shared__ ushort AsL[128][40];
    __shared__ ushort BsH[256][40];
    __shared__ ushort BsL[256][40];

    const int nt = blockIdx.x;          // 0 = fw cols, 1 = bw cols
    const int mt = blockIdx.y;          // 0..499
    const int m0 = mt * 128;
    const float* W   = nt ? Wb : Wf;
    const float* bia = nt ? biasb : biasf;

    const int tid  = threadIdx.x;
    const int lane = tid & 63;
    const int wv   = tid >> 6;          // wave 0..3
    const int wr   = wv >> 1;           // row-half
    const int wc   = wv & 1;            // col-half (128 cols each)
    const int l15  = lane & 15;
    const int l4   = lane >> 4;

    const int as  = tid & 7;            // A k-slot (4 floats)
    const int arr = tid >> 3;           // A row 0..31 (x4 row-groups)

    f32x4 acc[4][8];
#pragma unroll
    for (int i = 0; i < 4; i++)
#pragma unroll
        for (int j = 0; j < 8; j++)
            acc[i][j] = (f32x4){0.f, 0.f, 0.f, 0.f};

    float4 av[4];
    float bv[32];

#define PROJ_LOAD(K0_) do {                                                   \
        const int ka_ = (K0_) + as * 4;                                       \
        const bool aok_ = (ka_ + 3) < CIN;                                    \
        _Pragma("unroll")                                                     \
        for (int i_ = 0; i_ < 4; i_++) {                                      \
            av[i_] = make_float4(0.f, 0.f, 0.f, 0.f);                         \
            if (aok_)                                                         \
                av[i_] = *(const float4*)&x[(size_t)(m0 + arr + 32 * i_) * CIN + ka_]; \
        }                                                                     \
        _Pragma("unroll")                                                     \
        for (int j_ = 0; j_ < 32; j_++) {                                     \
            const int kb_ = (K0_) + j_;                                       \
            bv[j_] = (kb_ < CIN) ? W[(size_t)kb_ * HID + tid] : 0.f;          \
        }                                                                     \
    } while (0)

#define PROJ_CVT_WRITE() do {                                                 \
        _Pragma("unroll")                                                     \
        for (int i_ = 0; i_ < 4; i_++) {                                      \
            const int row_ = arr + 32 * i_;                                   \
            ushort4 h_, l_;                                                   \
            h_.x = f2bf_rne(av[i_].x); l_.x = f2bf_rne(__fsub_rn(av[i_].x, bf2f(h_.x))); \
            h_.y = f2bf_rne(av[i_].y); l_.y = f2bf_rne(__fsub_rn(av[i_].y, bf2f(h_.y))); \
            h_.z = f2bf_rne(av[i_].z); l_.z = f2bf_rne(__fsub_rn(av[i_].z, bf2f(h_.z))); \
            h_.w = f2bf_rne(av[i_].w); l_.w = f2bf_rne(__fsub_rn(av[i_].w, bf2f(h_.w))); \
            *(ushort4*)&AsH[row_][as * 4] = h_;                               \
            *(ushort4*)&AsL[row_][as * 4] = l_;                               \
        }                                                                     \
        _Pragma("unroll")                                                     \
        for (int q_ = 0; q_ < 8; q_++) {                                      \
            ushort4 h_, l_;                                                   \
            float v0_ = bv[q_ * 4 + 0], v1_ = bv[q_ * 4 + 1];                 \
            float v2_ = bv[q_ * 4 + 2], v3_ = bv[q_ * 4 + 3];                 \
            h_.x = f2bf_rne(v0_); l_.x = f2bf_rne(__fsub_rn(v0_, bf2f(h_.x))); \
            h_.y = f2bf_rne(v1_); l_.y = f2bf_rne(__fsub_rn(v1_, bf2f(h_.y))); \
            h_.z = f2bf_rne(v2_); l_.z = f2bf_rne(__fsub_rn(v2_, bf2f(h_.z))); \
            h_.w = f2bf_rne(v3_); l_.w = f2bf_rne(__fsub_rn(v3_, bf2f(h_.w))); \
            *(ushort4*)&BsH[tid][q_ * 4] = h_;                               \
            *(ushort4*)&BsL[tid][q_ * 4] = l_;                               \
        }                                                                     \
    } while (0)

    PROJ_LOAD(0);
    PROJ_CVT_WRITE();

    for (int kt = 0; kt < KSTEPS; kt++) {
        __syncthreads();                 // tile kt writes visible
        if (kt + 1 < KSTEPS)
            PROJ_LOAD((kt + 1) * 32);    // next loads land during MFMA

#pragma unroll
        for (int fc = 0; fc < 8; fc++) {
            const bf16x8 bHf = *(const bf16x8*)&BsH[wc * 128 + fc * 16 + l15][l4 * 8];
            const bf16x8 bLf = *(const bf16x8*)&BsL[wc * 128 + fc * 16 + l15][l4 * 8];
#pragma unroll
            for (int fr = 0; fr < 4; fr++) {
                const bf16x8 aHf = *(const bf16x8*)&AsH[wr * 64 + fr * 16 + l15][l4 * 8];
                const bf16x8 aLf = *(const bf16x8*)&AsL[wr * 64 + fr * 16 + l15][l4 * 8];
                acc[fr][fc] = __builtin_amdgcn_mfma_f32_16x16x32_bf16(
                    aHf, bHf, acc[fr][fc], 0, 0, 0);
                acc[fr][fc] = __builtin_amdgcn_mfma_f32_16x16x32_bf16(
                    aHf, bLf, acc[fr][fc], 0, 0, 0);
                acc[fr][fc] = __builtin_amdgcn_mfma_f32_16x16x32_bf16(
                    aLf, bHf, acc[fr][fc], 0, 0, 0);
            }
        }

        __syncthreads();                 // all reads of tile kt done
        if (kt + 1 < KSTEPS)
            PROJ_CVT_WRITE();
    }

#undef PROJ_LOAD
#undef PROJ_CVT_WRITE

#pragma unroll
    for (int fc = 0; fc < 8; fc++) {
        const int col = wc * 128 + fc * 16 + l15;      // 0..255 in direction
        const float bvs = bia[col];
#pragma unroll
        for (int fr = 0; fr < 4; fr++) {
#pragma unroll
            for (int j = 0; j < 4; j++) {
                const int row = m0 + wr * 64 + fr * 16 + l4 * 4 + j;
                P[(size_t)row * 512 + nt * HID + col] =
                    __fadd_rn(acc[fr][fc][j], bvs);
            }
        }
    }
}

// ---------------------------------------------------------------------------
// Kernel 2: MFMA scan — R6-exact structure with ONE change: the recurrent
// GEMM uses i8 MFMA (16x16x64, 2x K) on 14-bit-quantized W_rec:
//   q = rint(w/s2), s2 = cmax/16000; hi = (q+128)>>8, lo = q-256*hi
//   (hi in [-62,63], lo in [-128,127]); acc = s2 * (256*accH + accL)
// i32 accumulation exact; 256*accH+accL <= 4.2M -> exact fp32 convert; one
// rounding at the scale. Per-weight error <= s2/2 ~ 2e-6: same perturbation
// class as the proven bf16 hi/lo residual. 32 bf16 MFMA -> 16 i8 MFMA per
// wave per step (MFMA floor ~halved). Readout/LIF/pv timing R6-identical.
// ---------------------------------------------------------------------------
__global__ __launch_bounds__(512, 2) void scan_mfma(
    const float* __restrict__ P,
    const float* __restrict__ Wrecf, const float* __restrict__ brecf,
    const float* __restrict__ taumf, const float* __restrict__ tauaf,
    const float* __restrict__ Wrecb, const float* __restrict__ brecb,
    const float* __restrict__ taumb, const float* __restrict__ tauab,
    const float* __restrict__ Wout, const float* __restrict__ taumo,
    float* __restrict__ Pst)
{
    const int g  = blockIdx.x;          // batch group: b0..b0+15
    const int d  = blockIdx.y;          // 0 = fw, 1 = bw
    const int b0 = g * 16;
    const bool fw = (d == 0);

    const int tid  = threadIdx.x;
    const int lane = tid & 63;
    const int w    = tid >> 6;          // wave 0..7
    const int l15  = lane & 15;
    const int l4   = lane >> 4;

    __shared__ ushort Sp[2][16][264];           // bf16 spikes (readout path)
    __shared__ signed char Sp8[2][16][272];     // i8 spikes (recurrent path)

    {   // zero both spike buffers (step -1 spikes = 0)
        ushort* p = &Sp[0][0][0];
        for (int i = tid; i < 2 * 16 * 264; i += 512) p[i] = 0;
        signed char* p8 = &Sp8[0][0][0];
        for (int i = tid; i < 2 * 16 * 272; i += 512) p8[i] = 0;
    }

    const float* Wrec = fw ? Wrecf : Wrecb;

    // ---- W_rec i8 hi/lo fragments (64 VGPR) + per-column scales
    float s2_[2];
    i32x4 b8h[2][4], b8l[2][4];
#pragma unroll
    for (int t = 0; t < 2; t++) {
        const int c = w * 32 + t * 16 + l15;
        float cmax = 0.f;
        for (int k = 0; k < HID; k++)
            cmax = fmaxf(cmax, fabsf(Wrec[(size_t)k * HID + c]));
        cmax = fmaxf(cmax, 1e-30f);
        const float s2  = __fdiv_rn(cmax, 16000.f);
        const float inv = __fdiv_rn(16000.f, cmax);
        s2_[t] = s2;
#pragma unroll
        for (int kt = 0; kt < 4; kt++) {
            int hw[4], lw[4];
#pragma unroll
            for (int wd = 0; wd < 4; wd++) {
                int hb = 0, lb = 0;
#pragma unroll
                for (int byt = 0; byt < 4; byt++) {
                    const int k = kt * 64 + l4 * 16 + wd * 4 + byt;
                    const float v = Wrec[(size_t)k * HID + c];
                    const int q  = (int)lrintf(__fmul_rn(v, inv));
                    const int hi = (q + 128) >> 8;
                    const int lo = q - (hi << 8);
                    hb |= (hi & 255) << (8 * byt);
                    lb |= (lo & 255) << (8 * byt);
                }
                hw[wd] = hb; lw[wd] = lb;
            }
            b8h[t][kt] = (i32x4){hw[0], hw[1], hw[2], hw[3]};
            b8l[t][kt] = (i32x4){lw[0], lw[1], lw[2], lw[3]};
        }
    }

    // ---- W_out fragments for this wave's 32-k slice (hi+lo bf16)
    bf16x8 woh[2], wol[2];
#pragma unroll
    for (int t = 0; t < 2; t++) {
        const int o = t * 16 + l15;
#pragma unroll
        for (int j = 0; j < 8; j++) {
            float v = 0.f;
            if (o < OUT_N)
                v = Wout[(size_t)(d * HID + w * 32 + l4 * 8 + j) * OUT_N + o];
            const ushort h = f2bf_rne(v);
            const ushort l = f2bf_rne(__fsub_rn(v, bf2f(h)));
            woh[t][j] = (short)h;
            wol[t][j] = (short)l;
        }
    }

    // ---- LIF constants for this thread's 2 columns
    float alpha_[2], ro_[2], omA_[2], omR_[2], brc_[2];
#pragma unroll
    for (int t = 0; t < 2; t++) {
        const int c = w * 32 + t * 16 + l15;
        alpha_[t] = expf(__fdiv_rn(-1.f, fw ? taumf[c] : taumb[c]));
        ro_[t]    = expf(__fdiv_rn(-1.f, fw ? tauaf[c] : tauab[c]));
        omA_[t]   = __fsub_rn(1.f, alpha_[t]);
        omR_[t]   = __fsub_rn(1.f, ro_[t]);
        brc_[t]   = fw ? brecf[c] : brecb[c];
    }
    // ---- readout constants
    float ao_[2], omo_[2];
#pragma unroll
    for (int t = 0; t < 2; t++) {
        const int o = t * 16 + l15;
        if (o < OUT_N) {
            ao_[t]  = expf(__fdiv_rn(-1.f, taumo[o]));
            omo_[t] = __fsub_rn(1.f, ao_[t]);
        } else { ao_[t] = 0.f; omo_[t] = 0.f; }
    }

    float mem[2][4], bbv[2][4], spkv[2][4], z[2][4];
#pragma unroll
    for (int t = 0; t < 2; t++)
#pragma unroll
        for (int j = 0; j < 4; j++) {
            mem[t][j] = 0.f; bbv[t][j] = 0.01f; spkv[t][j] = 0.f; z[t][j] = 0.f;
        }

    // pv prefetch for s=0
    float pv[2][4];
    {
        const int srow = fw ? 0 : (S_LEN - 1);
#pragma unroll
        for (int t = 0; t < 2; t++)
#pragma unroll
            for (int j = 0; j < 4; j++)
                pv[t][j] = P[((size_t)(b0 + l4 * 4 + j) * S_LEN + srow) * 512
                             + d * HID + w * 32 + t * 16 + l15];
    }

    for (int s = 0; s < S_LEN; s++) {
        const int cur = s & 1, prev = cur ^ 1;

        // prefetch next step's projection BEFORE the barrier (R6 exact)
        float pv_next[2][4];
        {
            const int sn   = (s + 1 < S_LEN) ? s + 1 : S_LEN - 1;
            const int srow = fw ? sn : (S_LEN - 1 - sn);
#pragma unroll
            for (int t = 0; t < 2; t++)
#pragma unroll
                for (int j = 0; j < 4; j++)
                    pv_next[t][j] = P[((size_t)(b0 + l4 * 4 + j) * S_LEN + srow) * 512
                                      + d * HID + w * 32 + t * 16 + l15];
        }

        __syncthreads();   // Sp/Sp8[prev] complete from all waves

        // ---- recurrent GEMM (i8): accH/accL i32, 4 indep 4-deep chains
        i32x4 accH0 = (i32x4){0, 0, 0, 0}, accL0 = (i32x4){0, 0, 0, 0};
        i32x4 accH1 = (i32x4){0, 0, 0, 0}, accL1 = (i32x4){0, 0, 0, 0};
#pragma unroll
        for (int kt = 0; kt < 4; kt++) {
            const i32x4 a8 = *(const i32x4*)&Sp8[prev][l15][kt * 64 + l4 * 16];
            accH0 = __builtin_amdgcn_mfma_i32_16x16x64_i8(a8, b8h[0][kt], accH0, 0, 0, 0);
            accL0 = __builtin_amdgcn_mfma_i32_16x16x64_i8(a8, b8l[0][kt], accL0, 0, 0, 0);
            accH1 = __builtin_amdgcn_mfma_i32_16x16x64_i8(a8, b8h[1][kt], accH1, 0, 0, 0);
            accL1 = __builtin_amdgcn_mfma_i32_16x16x64_i8(a8, b8l[1][kt], accL1, 0, 0, 0);
        }

        // ---- adaptive-LIF update (exact reference rounding order; accv =
        // s2 * exact-int, one rounding — replaces the bf16-pair accv)
#pragma unroll
        for (int t = 0; t < 2; t++) {
#pragma unroll
            for (int j = 0; j < 4; j++) {
                const int th = t ? accH1[j] : accH0[j];
                const int tl = t ? accL1[j] : accL0[j];
                const float accv = __fmul_rn(s2_[t], (float)(th * 256 + tl));
                const float dd = __fadd_rn(__fadd_rn(pv[t][j], accv), brc_[t]);
                bbv[t][j] = __fadd_rn(__fmul_rn(ro_[t], bbv[t][j]),
                                      __fmul_rn(omR_[t], spkv[t][j]));
                const float thr = __fadd_rn(0.01f, __fmul_rn(1.8f, bbv[t][j]));
                mem[t][j] = __fsub_rn(
                    __fadd_rn(__fmul_rn(mem[t][j], alpha_[t]),
                              __fmul_rn(omA_[t], dd)),
                    __fmul_rn(thr, spkv[t][j]));
                const bool sp = __fsub_rn(mem[t][j], thr) > 0.f;
                spkv[t][j] = sp ? 1.f : 0.f;
                const int row = l4 * 4 + j;
                const int col = w * 32 + t * 16 + l15;
                Sp[cur][row][col]  = sp ? (ushort)0x3F80 : (ushort)0;
                Sp8[cur][row][col] = sp ? (signed char)1 : (signed char)0;
            }
        }

        // make own-wave spike writes visible to own-wave cross-lane reads
        asm volatile("s_waitcnt lgkmcnt(0)" ::: "memory");
        __builtin_amdgcn_sched_barrier(0);

        // ---- readout partial: this wave's 32-col k-slice of spk(cur)
        {
            const bf16x8 ar = *(const bf16x8*)&Sp[cur][l15][w * 32 + l4 * 8];
            f32x4 S0 = (f32x4){0.f, 0.f, 0.f, 0.f};
            f32x4 S1 = (f32x4){0.f, 0.f, 0.f, 0.f};
            S0 = __builtin_amdgcn_mfma_f32_16x16x32_bf16(ar, woh[0], S0, 0, 0, 0);
            S0 = __builtin_amdgcn_mfma_f32_16x16x32_bf16(ar, wol[0], S0, 0, 0, 0);
            S1 = __builtin_amdgcn_mfma_f32_16x16x32_bf16(ar, woh[1], S1, 0, 0, 0);
            S1 = __builtin_amdgcn_mfma_f32_16x16x32_bf16(ar, wol[1], S1, 0, 0, 0);
#pragma unroll
            for (int j = 0; j < 4; j++) {
                z[0][j] = __fmaf_rn(ao_[0], z[0][j], __fmul_rn(omo_[0], S0[j]));
                z[1][j] = __fmaf_rn(ao_[1], z[1][j], __fmul_rn(omo_[1], S1[j]));
            }
        }

#pragma unroll
        for (int t = 0; t < 2; t++)
#pragma unroll
            for (int j = 0; j < 4; j++) pv[t][j] = pv_next[t][j];
    }

    __syncthreads();   // all waves done reading P rows we now overwrite

    // ---- stash per-wave readout partials into consumed P rows
    float* stash = Pst + ((size_t)b0 * S_LEN) * 512 + d * HID;
#pragma unroll
    for (int j = 0; j < 4; j++) {
        const int r = l4 * 4 + j;
        const int idx0 = w * 320 + r * 16 + l15;
        stash[(size_t)(idx0 >> 8) * 512 + (idx0 & 255)] = z[0][j];
        if (l15 < 4) {
            const int idx1 = w * 320 + 256 + r * 4 + l15;
            stash[(size_t)(idx1 >> 8) * 512 + (idx1 & 255)] = z[1][j];
        }
    }
}

// ---------------------------------------------------------------------------
// Kernel 3: merge stashed partials + bias closed form + log_softmax.
// ---------------------------------------------------------------------------
__global__ __launch_bounds__(64) void merge_out(
    const float* __restrict__ Pst, const float* __restrict__ bout,
    const float* __restrict__ taumo, float* __restrict__ out)
{
    const int bb = blockIdx.x;
    const int o  = threadIdx.x;         // active 0..19
    const int g  = bb >> 4, r = bb & 15;

    float val = 0.f, v = -3.0e38f;
    if (o < OUT_N) {
        float tot = 0.f;
#pragma unroll
        for (int d2 = 0; d2 < 2; d2++) {
            const float* stash = Pst + ((size_t)(g * 16) * S_LEN) * 512 + d2 * HID;
#pragma unroll
            for (int w2 = 0; w2 < 8; w2++) {
                const int idx = (o < 16) ? (w2 * 320 + r * 16 + o)
                                         : (w2 * 320 + 256 + r * 4 + (o - 16));
                tot = __fadd_rn(tot, stash[(size_t)(idx >> 8) * 512 + (idx & 255)]);
            }
        }
        const float aS = expf(__fdiv_rn(-(float)S_LEN, taumo[o]));
        val = __fadd_rn(tot, __fmul_rn(bout[o], __fsub_rn(1.f, aS)));
        v = val;
    }
    float mx = v;
#pragma unroll
    for (int d2 = 1; d2 < 64; d2 <<= 1)
        mx = fmaxf(mx, __shfl_xor(mx, d2, 64));
    float e = (o < OUT_N) ? expf(__fsub_rn(val, mx)) : 0.f;
#pragma unroll
    for (int d2 = 1; d2 < 64; d2 <<= 1)
        e += __shfl_xor(e, d2, 64);
    if (o < OUT_N)
        out[(size_t)bb * OUT_N + o] =
            __fsub_rn(__fsub_rn(val, mx), logf(e));
}

// ---------------------------------------------------------------------------
extern "C" void kernel_launch(void* const* d_in, const int* in_sizes, int n_in,
                              void* d_out, int out_size, void* d_ws, size_t ws_size,
                              hipStream_t stream) {
    const float* x         = (const float*)d_in[0];
    const float* W_in_f    = (const float*)d_in[1];
    const float* b_in_f    = (const float*)d_in[2];
    const float* W_rec_f   = (const float*)d_in[3];
    const float* b_rec_f   = (const float*)d_in[4];
    const float* tau_m_f   = (const float*)d_in[5];
    const float* tau_adp_f = (const float*)d_in[6];
    const float* W_in_b    = (const float*)d_in[7];
    const float* b_in_b    = (const float*)d_in[8];
    const float* W_rec_b   = (const float*)d_in[9];
    const float* b_rec_b   = (const float*)d_in[10];
    const float* tau_m_b   = (const float*)d_in[11];
    const float* tau_adp_b = (const float*)d_in[12];
    const float* W_out     = (const float*)d_in[13];
    const float* b_out     = (const float*)d_in[14];
    const float* tau_m_o   = (const float*)d_in[15];
    float* out = (float*)d_out;
    float* P   = (float*)d_ws;

    proj_mfma<<<dim3(2, 500), dim3(256), 0, stream>>>(
        x, W_in_f, W_in_b, b_in_f, b_in_b, P);
    scan_mfma<<<dim3(16, 2), dim3(512), 0, stream>>>(
        P, W_rec_f, b_rec_f, tau_m_f, tau_adp_f,
        W_rec_b, b_rec_b, tau_m_b, tau_adp_b,
        W_out, tau_m_o, P);
    merge_out<<<dim3(BATCH), dim3(64), 0, stream>>>(
        P, b_out, tau_m_o, out);
}

// Round 19
// 455.143 us; speedup vs baseline: 1.1231x; 1.1205x over previous
//
#include <hip/hip_runtime.h>
#include <cstdint>
#include <cstddef>

#define S_LEN 250
#define BATCH 256
#define CIN   700
#define HID   256
#define OUT_N 20
#define KSTEPS 22   // ceil(700/32)

typedef __attribute__((ext_vector_type(8))) short bf16x8;
typedef __attribute__((ext_vector_type(4))) float f32x4;

__device__ __forceinline__ ushort f2bf_rne(float f) {
    uint u = __float_as_uint(f);
    uint r = (u + 0x7FFFu + ((u >> 16) & 1u)) >> 16;
    return (ushort)r;
}
__device__ __forceinline__ float bf2f(ushort h) {
    return __uint_as_float(((uint)h) << 16);
}

// ---------------------------------------------------------------------------
// Kernel 1: input projection GEMM via bf16x3 split MFMA (R14 form — best
// measured ~158us; bit-identical P). FROZEN.
// ---------------------------------------------------------------------------
__global__ __launch_bounds__(256) void proj_mfma(
    const float* __restrict__ x,
    const float* __restrict__ Wf, const float* __restrict__ Wb,
    const float* __restrict__ biasf, const float* __restrict__ biasb,
    float* __restrict__ P)
{
    __shared__ ushort AsH[128][40];
    __shared__ ushort AsL[128][40];
    __shared__ ushort BsH[256][40];
    __shared__ ushort BsL[256][40];

    const int nt = blockIdx.x;          // 0 = fw cols, 1 = bw cols
    const int mt = blockIdx.y;          // 0..499
    const int m0 = mt * 128;
    const float* W   = nt ? Wb : Wf;
    const float* bia = nt ? biasb : biasf;

    const int tid  = threadIdx.x;
    const int lane = tid & 63;
    const int wv   = tid >> 6;          // wave 0..3
    const int wr   = wv >> 1;           // row-half
    const int wc   = wv & 1;            // col-half (128 cols each)
    const int l15  = lane & 15;
    const int l4   = lane >> 4;

    const int as  = tid & 7;            // A k-slot (4 floats)
    const int arr = tid >> 3;           // A row 0..31 (x4 row-groups)

    f32x4 acc[4][8];
#pragma unroll
    for (int i = 0; i < 4; i++)
#pragma unroll
        for (int j = 0; j < 8; j++)
            acc[i][j] = (f32x4){0.f, 0.f, 0.f, 0.f};

    float4 av[4];
    float bv[32];

#define PROJ_LOAD(K0_) do {                                                   \
        const int ka_ = (K0_) + as * 4;                                       \
        const bool aok_ = (ka_ + 3) < CIN;                                    \
        _Pragma("unroll")                                                     \
        for (int i_ = 0; i_ < 4; i_++) {                                      \
            av[i_] = make_float4(0.f, 0.f, 0.f, 0.f);                         \
            if (aok_)                                                         \
                av[i_] = *(const float4*)&x[(size_t)(m0 + arr + 32 * i_) * CIN + ka_]; \
        }                                                                     \
        _Pragma("unroll")                                                     \
        for (int j_ = 0; j_ < 32; j_++) {                                     \
            const int kb_ = (K0_) + j_;                                       \
            bv[j_] = (kb_ < CIN) ? W[(size_t)kb_ * HID + tid] : 0.f;          \
        }                                                                     \
    } while (0)

#define PROJ_CVT_WRITE() do {                                                 \
        _Pragma("unroll")                                                     \
        for (int i_ = 0; i_ < 4; i_++) {                                      \
            const int row_ = arr + 32 * i_;                                   \
            ushort4 h_, l_;                                                   \
            h_.x = f2bf_rne(av[i_].x); l_.x = f2bf_rne(__fsub_rn(av[i_].x, bf2f(h_.x))); \
            h_.y = f2bf_rne(av[i_].y); l_.y = f2bf_rne(__fsub_rn(av[i_].y, bf2f(h_.y))); \
            h_.z = f2bf_rne(av[i_].z); l_.z = f2bf_rne(__fsub_rn(av[i_].z, bf2f(h_.z))); \
            h_.w = f2bf_rne(av[i_].w); l_.w = f2bf_rne(__fsub_rn(av[i_].w, bf2f(h_.w))); \
            *(ushort4*)&AsH[row_][as * 4] = h_;                               \
            *(ushort4*)&AsL[row_][as * 4] = l_;                               \
        }                                                                     \
        _Pragma("unroll")                                                     \
        for (int q_ = 0; q_ < 8; q_++) {                                      \
            ushort4 h_, l_;                                                   \
            float v0_ = bv[q_ * 4 + 0], v1_ = bv[q_ * 4 + 1];                 \
            float v2_ = bv[q_ * 4 + 2], v3_ = bv[q_ * 4 + 3];                 \
            h_.x = f2bf_rne(v0_); l_.x = f2bf_rne(__fsub_rn(v0_, bf2f(h_.x))); \
            h_.y = f2bf_rne(v1_); l_.y = f2bf_rne(__fsub_rn(v1_, bf2f(h_.y))); \
            h_.z = f2bf_rne(v2_); l_.z = f2bf_rne(__fsub_rn(v2_, bf2f(h_.z))); \
            h_.w = f2bf_rne(v3_); l_.w = f2bf_rne(__fsub_rn(v3_, bf2f(h_.w))); \
            *(ushort4*)&BsH[tid][q_ * 4] = h_;                               \
            *(ushort4*)&BsL[tid][q_ * 4] = l_;                               \
        }                                                                     \
    } while (0)

    PROJ_LOAD(0);
    PROJ_CVT_WRITE();

    for (int kt = 0; kt < KSTEPS; kt++) {
        __syncthreads();                 // tile kt writes visible
        if (kt + 1 < KSTEPS)
            PROJ_LOAD((kt + 1) * 32);    // next loads land during MFMA

#pragma unroll
        for (int fc = 0; fc < 8; fc++) {
            const bf16x8 bHf = *(const bf16x8*)&BsH[wc * 128 + fc * 16 + l15][l4 * 8];
            const bf16x8 bLf = *(const bf16x8*)&BsL[wc * 128 + fc * 16 + l15][l4 * 8];
#pragma unroll
            for (int fr = 0; fr < 4; fr++) {
                const bf16x8 aHf = *(const bf16x8*)&AsH[wr * 64 + fr * 16 + l15][l4 * 8];
                const bf16x8 aLf = *(const bf16x8*)&AsL[wr * 64 + fr * 16 + l15][l4 * 8];
                acc[fr][fc] = __builtin_amdgcn_mfma_f32_16x16x32_bf16(
                    aHf, bHf, acc[fr][fc], 0, 0, 0);
                acc[fr][fc] = __builtin_amdgcn_mfma_f32_16x16x32_bf16(
                    aHf, bLf, acc[fr][fc], 0, 0, 0);
                acc[fr][fc] = __builtin_amdgcn_mfma_f32_16x16x32_bf16(
                    aLf, bHf, acc[fr][fc], 0, 0, 0);
            }
        }

        __syncthreads();                 // all reads of tile kt done
        if (kt + 1 < KSTEPS)
            PROJ_CVT_WRITE();
    }

#undef PROJ_LOAD
#undef PROJ_CVT_WRITE

#pragma unroll
    for (int fc = 0; fc < 8; fc++) {
        const int col = wc * 128 + fc * 16 + l15;      // 0..255 in direction
        const float bvs = bia[col];
#pragma unroll
        for (int fr = 0; fr < 4; fr++) {
#pragma unroll
            for (int j = 0; j < 4; j++) {
                const int row = m0 + wr * 64 + fr * 16 + l4 * 4 + j;
                P[(size_t)row * 512 + nt * HID + col] =
                    __fadd_rn(acc[fr][fc][j], bvs);
            }
        }
    }
}

// ---------------------------------------------------------------------------
// Kernel 2: MFMA scan — EXACT R6 form (best measured: 293-294us, absmax
// 0.0625). Seven variants measured worse or neutral (R7 spill, R9/R10 pv
// timing, R13 delayed readout, R17 16-wave, R18 i8): the 250-step serial
// loop's per-step chain (barrier + LDS round-trip + dependent MFMA + LIF)
// is this decomposition's floor. FROZEN.
// ---------------------------------------------------------------------------
__global__ __launch_bounds__(512, 2) void scan_mfma(
    const float* __restrict__ P,
    const float* __restrict__ Wrecf, const float* __restrict__ brecf,
    const float* __restrict__ taumf, const float* __restrict__ tauaf,
    const float* __restrict__ Wrecb, const float* __restrict__ brecb,
    const float* __restrict__ taumb, const float* __restrict__ tauab,
    const float* __restrict__ Wout, const float* __restrict__ taumo,
    float* __restrict__ Pst)
{
    const int g  = blockIdx.x;          // batch group: b0..b0+15
    const int d  = blockIdx.y;          // 0 = fw, 1 = bw
    const int b0 = g * 16;
    const bool fw = (d == 0);

    const int tid  = threadIdx.x;
    const int lane = tid & 63;
    const int w    = tid >> 6;          // wave 0..7
    const int l15  = lane & 15;
    const int l4   = lane >> 4;

    __shared__ ushort Sp[2][16][264];   // [buf][batch][col(+pad)] bf16 spikes

    {   // zero both spike buffers (step -1 spikes = 0)
        ushort* p = &Sp[0][0][0];
        for (int i = tid; i < 2 * 16 * 264; i += 512) p[i] = 0;
    }

    const float* Wrec = fw ? Wrecf : Wrecb;

    // ---- W_rec fragments (hi+lo bf16), register resident
    bf16x8 whf[8][2], wlf[8][2];
#pragma unroll
    for (int kt = 0; kt < 8; kt++)
#pragma unroll
        for (int ct = 0; ct < 2; ct++) {
            const int c = w * 32 + ct * 16 + l15;
#pragma unroll
            for (int j = 0; j < 8; j++) {
                const float v = Wrec[(size_t)(kt * 32 + l4 * 8 + j) * HID + c];
                const ushort h = f2bf_rne(v);
                const ushort l = f2bf_rne(__fsub_rn(v, bf2f(h)));
                whf[kt][ct][j] = (short)h;
                wlf[kt][ct][j] = (short)l;
            }
        }

    // ---- W_out fragments for this wave's 32-k slice (hi+lo)
    bf16x8 woh[2], wol[2];
#pragma unroll
    for (int t = 0; t < 2; t++) {
        const int o = t * 16 + l15;
#pragma unroll
        for (int j = 0; j < 8; j++) {
            float v = 0.f;
            if (o < OUT_N)
                v = Wout[(size_t)(d * HID + w * 32 + l4 * 8 + j) * OUT_N + o];
            const ushort h = f2bf_rne(v);
            const ushort l = f2bf_rne(__fsub_rn(v, bf2f(h)));
            woh[t][j] = (short)h;
            wol[t][j] = (short)l;
        }
    }

    // ---- LIF constants for this thread's 2 columns
    float alpha_[2], ro_[2], omA_[2], omR_[2], brc_[2];
#pragma unroll
    for (int t = 0; t < 2; t++) {
        const int c = w * 32 + t * 16 + l15;
        alpha_[t] = expf(__fdiv_rn(-1.f, fw ? taumf[c] : taumb[c]));
        ro_[t]    = expf(__fdiv_rn(-1.f, fw ? tauaf[c] : tauab[c]));
        omA_[t]   = __fsub_rn(1.f, alpha_[t]);
        omR_[t]   = __fsub_rn(1.f, ro_[t]);
        brc_[t]   = fw ? brecf[c] : brecb[c];
    }
    // ---- readout constants
    float ao_[2], omo_[2];
#pragma unroll
    for (int t = 0; t < 2; t++) {
        const int o = t * 16 + l15;
        if (o < OUT_N) {
            ao_[t]  = expf(__fdiv_rn(-1.f, taumo[o]));
            omo_[t] = __fsub_rn(1.f, ao_[t]);
        } else { ao_[t] = 0.f; omo_[t] = 0.f; }
    }

    float mem[2][4], bbv[2][4], spkv[2][4], z[2][4];
#pragma unroll
    for (int t = 0; t < 2; t++)
#pragma unroll
        for (int j = 0; j < 4; j++) {
            mem[t][j] = 0.f; bbv[t][j] = 0.01f; spkv[t][j] = 0.f; z[t][j] = 0.f;
        }

    // pv prefetch for s=0
    float pv[2][4];
    {
        const int srow = fw ? 0 : (S_LEN - 1);
#pragma unroll
        for (int t = 0; t < 2; t++)
#pragma unroll
            for (int j = 0; j < 4; j++)
                pv[t][j] = P[((size_t)(b0 + l4 * 4 + j) * S_LEN + srow) * 512
                             + d * HID + w * 32 + t * 16 + l15];
    }

    for (int s = 0; s < S_LEN; s++) {
        const int cur = s & 1, prev = cur ^ 1;

        // prefetch next step's projection BEFORE the barrier (R6 exact)
        float pv_next[2][4];
        {
            const int sn   = (s + 1 < S_LEN) ? s + 1 : S_LEN - 1;
            const int srow = fw ? sn : (S_LEN - 1 - sn);
#pragma unroll
            for (int t = 0; t < 2; t++)
#pragma unroll
                for (int j = 0; j < 4; j++)
                    pv_next[t][j] = P[((size_t)(b0 + l4 * 4 + j) * S_LEN + srow) * 512
                                      + d * HID + w * 32 + t * 16 + l15];
        }

        __syncthreads();   // Sp[prev] complete from all waves

        // ---- recurrent GEMM: D[batch][col] += spk(prev) @ W_rec
        f32x4 acc[2];
        acc[0] = (f32x4){0.f, 0.f, 0.f, 0.f};
        acc[1] = (f32x4){0.f, 0.f, 0.f, 0.f};
#pragma unroll
        for (int kt = 0; kt < 8; kt++) {
            const bf16x8 a = *(const bf16x8*)&Sp[prev][l15][kt * 32 + l4 * 8];
            acc[0] = __builtin_amdgcn_mfma_f32_16x16x32_bf16(a, whf[kt][0], acc[0], 0, 0, 0);
            acc[0] = __builtin_amdgcn_mfma_f32_16x16x32_bf16(a, wlf[kt][0], acc[0], 0, 0, 0);
            acc[1] = __builtin_amdgcn_mfma_f32_16x16x32_bf16(a, whf[kt][1], acc[1], 0, 0, 0);
            acc[1] = __builtin_amdgcn_mfma_f32_16x16x32_bf16(a, wlf[kt][1], acc[1], 0, 0, 0);
        }

        // ---- adaptive-LIF update on the C/D fragment (exact ref rounding)
#pragma unroll
        for (int t = 0; t < 2; t++) {
#pragma unroll
            for (int j = 0; j < 4; j++) {
                const float dd = __fadd_rn(__fadd_rn(pv[t][j], acc[t][j]), brc_[t]);
                bbv[t][j] = __fadd_rn(__fmul_rn(ro_[t], bbv[t][j]),
                                      __fmul_rn(omR_[t], spkv[t][j]));
                const float thr = __fadd_rn(0.01f, __fmul_rn(1.8f, bbv[t][j]));
                mem[t][j] = __fsub_rn(
                    __fadd_rn(__fmul_rn(mem[t][j], alpha_[t]),
                              __fmul_rn(omA_[t], dd)),
                    __fmul_rn(thr, spkv[t][j]));
                const bool sp = __fsub_rn(mem[t][j], thr) > 0.f;
                spkv[t][j] = sp ? 1.f : 0.f;
                Sp[cur][l4 * 4 + j][w * 32 + t * 16 + l15] =
                    sp ? (ushort)0x3F80 : (ushort)0;
            }
        }

        // make own-wave spike writes visible to own-wave cross-lane reads
        asm volatile("s_waitcnt lgkmcnt(0)" ::: "memory");
        __builtin_amdgcn_sched_barrier(0);

        // ---- readout partial: this wave's 32-col k-slice of spk(cur)
        {
            const bf16x8 ar = *(const bf16x8*)&Sp[cur][l15][w * 32 + l4 * 8];
            f32x4 S0 = (f32x4){0.f, 0.f, 0.f, 0.f};
            f32x4 S1 = (f32x4){0.f, 0.f, 0.f, 0.f};
            S0 = __builtin_amdgcn_mfma_f32_16x16x32_bf16(ar, woh[0], S0, 0, 0, 0);
            S0 = __builtin_amdgcn_mfma_f32_16x16x32_bf16(ar, wol[0], S0, 0, 0, 0);
            S1 = __builtin_amdgcn_mfma_f32_16x16x32_bf16(ar, woh[1], S1, 0, 0, 0);
            S1 = __builtin_amdgcn_mfma_f32_16x16x32_bf16(ar, wol[1], S1, 0, 0, 0);
#pragma unroll
            for (int j = 0; j < 4; j++) {
                z[0][j] = __fmaf_rn(ao_[0], z[0][j], __fmul_rn(omo_[0], S0[j]));
                z[1][j] = __fmaf_rn(ao_[1], z[1][j], __fmul_rn(omo_[1], S1[j]));
            }
        }

#pragma unroll
        for (int t = 0; t < 2; t++)
#pragma unroll
            for (int j = 0; j < 4; j++) pv[t][j] = pv_next[t][j];
    }

    __syncthreads();   // all waves done reading P rows we now overwrite

    // ---- stash per-wave readout partials into consumed P rows
    float* stash = Pst + ((size_t)b0 * S_LEN) * 512 + d * HID;
#pragma unroll
    for (int j = 0; j < 4; j++) {
        const int r = l4 * 4 + j;
        const int idx0 = w * 320 + r * 16 + l15;
        stash[(size_t)(idx0 >> 8) * 512 + (idx0 & 255)] = z[0][j];
        if (l15 < 4) {
            const int idx1 = w * 320 + 256 + r * 4 + l15;
            stash[(size_t)(idx1 >> 8) * 512 + (idx1 & 255)] = z[1][j];
        }
    }
}

// ---------------------------------------------------------------------------
// Kernel 3: merge stashed partials + bias closed form + log_softmax.
// ---------------------------------------------------------------------------
__global__ __launch_bounds__(64) void merge_out(
    const float* __restrict__ Pst, const float* __restrict__ bout,
    const float* __restrict__ taumo, float* __restrict__ out)
{
    const int bb = blockIdx.x;
    const int o  = threadIdx.x;         // active 0..19
    const int g  = bb >> 4, r = bb & 15;

    float val = 0.f, v = -3.0e38f;
    if (o < OUT_N) {
        float tot = 0.f;
#pragma unroll
        for (int d2 = 0; d2 < 2; d2++) {
            const float* stash = Pst + ((size_t)(g * 16) * S_LEN) * 512 + d2 * HID;
#pragma unroll
            for (int w2 = 0; w2 < 8; w2++) {
                const int idx = (o < 16) ? (w2 * 320 + r * 16 + o)
                                         : (w2 * 320 + 256 + r * 4 + (o - 16));
                tot = __fadd_rn(tot, stash[(size_t)(idx >> 8) * 512 + (idx & 255)]);
            }
        }
        const float aS = expf(__fdiv_rn(-(float)S_LEN, taumo[o]));
        val = __fadd_rn(tot, __fmul_rn(bout[o], __fsub_rn(1.f, aS)));
        v = val;
    }
    float mx = v;
#pragma unroll
    for (int d2 = 1; d2 < 64; d2 <<= 1)
        mx = fmaxf(mx, __shfl_xor(mx, d2, 64));
    float e = (o < OUT_N) ? expf(__fsub_rn(val, mx)) : 0.f;
#pragma unroll
    for (int d2 = 1; d2 < 64; d2 <<= 1)
        e += __shfl_xor(e, d2, 64);
    if (o < OUT_N)
        out[(size_t)bb * OUT_N + o] =
            __fsub_rn(__fsub_rn(val, mx), logf(e));
}

// ---------------------------------------------------------------------------
extern "C" void kernel_launch(void* const* d_in, const int* in_sizes, int n_in,
                              void* d_out, int out_size, void* d_ws, size_t ws_size,
                              hipStream_t stream) {
    const float* x         = (const float*)d_in[0];
    const float* W_in_f    = (const float*)d_in[1];
    const float* b_in_f    = (const float*)d_in[2];
    const float* W_rec_f   = (const float*)d_in[3];
    const float* b_rec_f   = (const float*)d_in[4];
    const float* tau_m_f   = (const float*)d_in[5];
    const float* tau_adp_f = (const float*)d_in[6];
    const float* W_in_b    = (const float*)d_in[7];
    const float* b_in_b    = (const float*)d_in[8];
    const float* W_rec_b   = (const float*)d_in[9];
    const float* b_rec_b   = (const float*)d_in[10];
    const float* tau_m_b   = (const float*)d_in[11];
    const float* tau_adp_b = (const float*)d_in[12];
    const float* W_out     = (const float*)d_in[13];
    const float* b_out     = (const float*)d_in[14];
    const float* tau_m_o   = (const float*)d_in[15];
    float* out = (float*)d_out;
    float* P   = (float*)d_ws;

    proj_mfma<<<dim3(2, 500), dim3(256), 0, stream>>>(
        x, W_in_f, W_in_b, b_in_f, b_in_b, P);
    scan_mfma<<<dim3(16, 2), dim3(512), 0, stream>>>(
        P, W_rec_f, b_rec_f, tau_m_f, tau_adp_f,
        W_rec_b, b_rec_b, tau_m_b, tau_adp_b,
        W_out, tau_m_o, P);
    merge_out<<<dim3(BATCH), dim3(64), 0, stream>>>(
        P, b_out, tau_m_o, out);
}